// Round 6
// baseline (367.318 us; speedup 1.0000x reference)
//
#include <hip/hip_runtime.h>
#include <hip/hip_bf16.h>

#define D_MODEL 512
#define D_STATE 32
#define BATCH 8
#define SEQ 4096
#define MROWS (BATCH * SEQ)
#define NBLK 1024

typedef __bf16 bf16;
typedef __bf16 bf16x4 __attribute__((ext_vector_type(4)));
typedef __bf16 bf16x8 __attribute__((ext_vector_type(8)));
typedef float f32x4 __attribute__((ext_vector_type(4)));

// ---------------- software grid barrier (all NBLK blocks co-resident) ----------------
// Counters zeroed via hipMemsetAsync before each launch. Release add, relaxed spin,
// acquire fence after. Bounded spin -> no hang even if something goes wrong.
__device__ __forceinline__ void gridbar(int* bar, int idx, int nblocks) {
  __syncthreads();
  if (threadIdx.x == 0) {
    __threadfence();  // release: make prior writes visible device-wide
    __hip_atomic_fetch_add(&bar[idx * 32], 1, __ATOMIC_RELEASE, __HIP_MEMORY_SCOPE_AGENT);
    int it = 0;
    while (__hip_atomic_load(&bar[idx * 32], __ATOMIC_RELAXED, __HIP_MEMORY_SCOPE_AGENT) < nblocks) {
      __builtin_amdgcn_s_sleep(2);
      if (++it > (1 << 22)) break;  // failsafe: fail loud, never hang
    }
    __threadfence();  // acquire: invalidate stale L1/L2
  }
  __syncthreads();
}

struct PreS { float sM[32][32]; float sX[32][32]; float red[256]; float sdt; };
struct UbS  { bf16 tile[2][64][32]; };
union SMemF { PreS pre; UbS ub; float scan[64]; };   // 9.25 KB max

// Stage a 4 KB [64][32]-bf16 tile via global_load_lds (linear LDS dest, 1 load/thread).
// XOR slot-swizzle on the GLOBAL source; read side applies the same XOR.
__device__ __forceinline__ void stage4k(const void* gbase, long row0, long rowStrideB,
                                        int kByte, void* lds, int tid) {
  const int boff = tid << 4;           // 0..4080
  const int r = boff >> 6;             // tile row (64 B per row)
  const int s = (boff >> 4) & 3;       // physical 16B slot
  const int cb = ((s ^ (r & 3)) << 4); // swizzled source slot
  const char* src = (const char*)gbase + (row0 + r) * rowStrideB + kByte + cb;
  __builtin_amdgcn_global_load_lds(
      (const __attribute__((address_space(1))) void*)src,
      (__attribute__((address_space(3))) void*)((char*)lds + boff), 16, 0, 0);
}

#define CHUNK 16
#define BURN 80
#define NCHUNK (SEQ / CHUNK)   // 256 chunks per batch, 2048 chains total

// ================== fused P0(convert+pre+CW+WD) -> P1(uB) -> P2(scan) ==================
__global__ __launch_bounds__(256, 4) void k_fused(
    const float* __restrict__ x, const float* __restrict__ A, const float* __restrict__ B,
    const float* __restrict__ C, const float* __restrict__ Dv, const float* __restrict__ log_dt,
    const float* __restrict__ W, float* __restrict__ fs,
    float* __restrict__ A_bar, bf16* __restrict__ Bhi, bf16* __restrict__ Blo,
    bf16* __restrict__ CW, bf16* __restrict__ WD, bf16* __restrict__ Sb,
    float* __restrict__ uB, bf16* __restrict__ xb, int* __restrict__ bar) {
  __shared__ SMemF sm;
  const int bid = blockIdx.x, t = threadIdx.x;
  const int w = t >> 6, lane = t & 63;
  const int l15 = lane & 15, kg = lane >> 4;
  const int kgs = kg ^ (l15 & 3);   // swizzled LDS read slot (row&3 == l15&3 at read sites)

  // ---------------- P0: x -> xb (all blocks, 32 rows each) ----------------
  {
    const long base = (long)bid * 32 * D_MODEL;
#pragma unroll
    for (int jj = 0; jj < 16; jj++) {
      const int idx = jj * 1024 + t * 4;
      const f32x4 v = *(const f32x4*)(x + base + idx);
      bf16x4 h;
      h[0] = (bf16)v[0]; h[1] = (bf16)v[1]; h[2] = (bf16)v[2]; h[3] = (bf16)v[3];
      *(bf16x4*)(xb + base + idx) = h;
    }
  }
  if (bid == 0) {
    // ---- precompute: dt, X=(I-0.5dt A)^-1 (lower-tri fwd-subst), A_bar, packed Bhi/Blo
    auto& P = sm.pre;
    float p = 0.f;
    for (int i = t; i < D_MODEL; i += 256) {
      float v = __expf(log_dt[i]);
      v = fminf(fmaxf(v, 1e-4f), 1.0f);
      p += v;
    }
    P.red[t] = p;
    __syncthreads();
    for (int s2 = 128; s2 > 0; s2 >>= 1) {
      if (t < s2) P.red[t] += P.red[t + s2];
      __syncthreads();
    }
    if (t == 0) P.sdt = P.red[0] * (1.0f / D_MODEL);
    __syncthreads();
    const float dt = P.sdt;
    for (int i = t; i < 1024; i += 256) {
      int r = i >> 5, c = i & 31;
      P.sM[r][c] = (r == c ? 1.f : 0.f) - 0.5f * dt * A[i];
    }
    __syncthreads();
    if (t < 32) {
      const int j = t;
      float xcol[32];
#pragma unroll
      for (int i = 0; i < 32; i++) {
        float sacc = 0.f;
#pragma unroll
        for (int k = 0; k < 32; k++) {
          if (k < i) sacc -= P.sM[i][k] * xcol[k];
        }
        float num = (i == j ? 1.f : 0.f) + sacc;
        xcol[i] = (i >= j) ? num / P.sM[i][i] : 0.f;
      }
      for (int i = 0; i < 32; i++) P.sX[i][j] = xcol[i];
    }
    __syncthreads();
    for (int i = t; i < 1024; i += 256) {   // A_bar = (I + 0.5dt A) @ X
      int r = i >> 5, c = i & 31;
      float s = 0.f;
      for (int k = 0; k < 32; k++) {
        float p2 = (r == k ? 1.f : 0.f) + 0.5f * dt * A[r * 32 + k];
        s += p2 * P.sX[k][c];
      }
      A_bar[i] = s;
    }
    // Packed B_bar = dt * X @ B, hi/lo bf16 split; thread t owns column k (coalesced).
#pragma unroll 1
    for (int q = 0; q < 2; q++) {
      const int k = q * 256 + t;
      float bcol[32];
#pragma unroll
      for (int kk = 0; kk < 32; kk++) bcol[kk] = B[kk * D_MODEL + k];
      const int kt = k >> 5, kg2 = (k >> 3) & 3, j = k & 7;
#pragma unroll 1
      for (int n = 0; n < 32; n++) {
        float s = 0.f;
#pragma unroll
        for (int kk = 0; kk < 32; kk++) s = fmaf(P.sX[n][kk], bcol[kk], s);
        s *= dt;
        const bf16 hi = (bf16)s;
        const float lo = s - (float)hi;
        const int pidx = ((kt * 4 + kg2) * 32 + n) * 8 + j;
        Bhi[pidx] = hi;
        Blo[pidx] = (bf16)lo;
      }
    }
  } else if (bid <= 64) {
    // CW = W@C, packed [e][n]
    const int idx = (bid - 1) * 256 + t;
    const int e = idx >> 5, n = idx & 31;
    float s = 0.f;
    for (int d = 0; d < D_MODEL; d++) s += W[e * D_MODEL + d] * C[d * D_STATE + n];
    CW[idx] = (bf16)s;
  } else if (bid <= 80) {
    // WD = W * D
#pragma unroll
    for (int jj = 0; jj < 16; jj++) {
      const int i = (bid - 65) * 16384 + jj * 1024 + t * 4;
      const f32x4 wv = *(const f32x4*)(W + i);
      const f32x4 dv = *(const f32x4*)(Dv + (i & 511));
      bf16x4 h;
#pragma unroll
      for (int q = 0; q < 4; q++) h[q] = (bf16)(wv[q] * dv[q]);
      *(bf16x4*)(WD + i) = h;
    }
  }
  gridbar(bar, 0, NBLK);

  // ---------------- P1: uB = xb @ (Bhi+Blo)^T  (blocks 0..511, 64 rows) ----------------
  if (bid < 512) {
    const long rowbase = (long)bid * 64;
    f32x4 acc[2];
    acc[0] = (f32x4)(0.0f); acc[1] = (f32x4)(0.0f);
    stage4k(xb, rowbase, 1024, 0, &sm.ub.tile[0][0][0], t);
    __syncthreads();
#pragma unroll 1
    for (int kt = 0; kt < 16; kt++) {
      const int cur = kt & 1;
      if (kt < 15) stage4k(xb, rowbase, 1024, (kt + 1) * 64, &sm.ub.tile[cur ^ 1][0][0], t);
      const bf16x8 af = *(const bf16x8*)&sm.ub.tile[cur][w * 16 + l15][kgs * 8];
      const int bo = ((kt * 4 + kg) * 32 + l15) * 8;
      const bf16x8 bh0 = *(const bf16x8*)(Bhi + bo);
      const bf16x8 bh1 = *(const bf16x8*)(Bhi + bo + 128);
      const bf16x8 bl0 = *(const bf16x8*)(Blo + bo);
      const bf16x8 bl1 = *(const bf16x8*)(Blo + bo + 128);
      acc[0] = __builtin_amdgcn_mfma_f32_16x16x32_bf16(af, bh0, acc[0], 0, 0, 0);
      acc[0] = __builtin_amdgcn_mfma_f32_16x16x32_bf16(af, bl0, acc[0], 0, 0, 0);
      acc[1] = __builtin_amdgcn_mfma_f32_16x16x32_bf16(af, bh1, acc[1], 0, 0, 0);
      acc[1] = __builtin_amdgcn_mfma_f32_16x16x32_bf16(af, bl1, acc[1], 0, 0, 0);
      __syncthreads();
    }
#pragma unroll
    for (int nf = 0; nf < 2; nf++) {
      const long r0 = rowbase + w * 16 + kg * 4;
      const int n = nf * 16 + l15;
#pragma unroll
      for (int jj = 0; jj < 4; jj++)
        uB[(r0 + jj) * D_STATE + n] = acc[nf][jj];
    }
  }
  gridbar(bar, 1, NBLK);

  // ---------------- P2: chunked tanh scan (all blocks, 2 chains each) ----------------
  if (t < 64) {
    const int g = t >> 5, n = t & 31;
    const int chain = bid * 2 + g;
    const int b = chain >> 8;           // 256 chunks per batch
    const int ch = chain & 255;
    const int cs = ch * CHUNK;
    const int t0 = cs - BURN;           // may be negative (u treated as 0 there)
    const int ce = cs + CHUNK;

    float a[32];
#pragma unroll
    for (int k = 0; k < 32; k += 4) {
      const f32x4 v = *(const f32x4*)(A_bar + n * 32 + k);
      a[k] = v[0]; a[k + 1] = v[1]; a[k + 2] = v[2]; a[k + 3] = v[3];
    }
    const float* ub = uB + (long)b * SEQ * D_STATE + n;
    bf16* sp = Sb + ((long)b * SEQ + cs) * D_STATE + n;
    float* myslot = &sm.scan[g * 32];

    float s = 0.f;
    float ubuf[8], unext[8];
#pragma unroll
    for (int i = 0; i < 8; i++) {
      const int tt = t0 + i;
      ubuf[i] = (tt >= 0) ? ub[(long)tt * D_STATE] : 0.f;
    }
    for (int tg = t0; tg < ce; tg += 8) {
      const int tn = tg + 8;
#pragma unroll
      for (int i = 0; i < 8; i++) {
        const int tt = tn + i;
        unext[i] = (tt >= 0 && tt < ce) ? ub[(long)tt * D_STATE] : 0.f;
      }
#pragma unroll
      for (int i = 0; i < 8; i++) {
        const int tt = tg + i;
        myslot[n] = s;   // ds_write_b32, wave-ordered before the reads below
        const f32x4 s0 = *(const f32x4*)(myslot + 0);
        const f32x4 s1 = *(const f32x4*)(myslot + 4);
        const f32x4 s2 = *(const f32x4*)(myslot + 8);
        const f32x4 s3 = *(const f32x4*)(myslot + 12);
        const f32x4 s4 = *(const f32x4*)(myslot + 16);
        const f32x4 s5 = *(const f32x4*)(myslot + 20);
        const f32x4 s6 = *(const f32x4*)(myslot + 24);
        const f32x4 s7 = *(const f32x4*)(myslot + 28);
        float acc0 = ubuf[i], acc1 = 0.f, acc2 = 0.f, acc3 = 0.f;
#pragma unroll
        for (int q = 0; q < 4; q++) {
          acc0 = fmaf(a[0 + q],  s0[q], acc0);
          acc1 = fmaf(a[4 + q],  s1[q], acc1);
          acc2 = fmaf(a[8 + q],  s2[q], acc2);
          acc3 = fmaf(a[12 + q], s3[q], acc3);
          acc0 = fmaf(a[16 + q], s4[q], acc0);
          acc1 = fmaf(a[20 + q], s5[q], acc1);
          acc2 = fmaf(a[24 + q], s6[q], acc2);
          acc3 = fmaf(a[28 + q], s7[q], acc3);
        }
        const float z = (acc0 + acc1) + (acc2 + acc3);
        const float e = __expf(2.f * z);
        const float r = __builtin_amdgcn_rcpf(e + 1.f);
        s = fmaf(-2.f, r, 1.f);
        if (tt >= cs) sp[(long)(tt - cs) * D_STATE] = (bf16)s;
      }
#pragma unroll
      for (int i = 0; i < 8; i++) ubuf[i] = unext[i];
    }
    if (ch == NCHUNK - 1) fs[b * D_STATE + n] = s;
  }
}

// ---------------- K5: out = S@CW^T + xb@WD^T + b  (bf16 MFMA, 128x128 tile) ----------------
__device__ __forceinline__ void stage_tile(const void* gbase, long row0, long rowStrideB,
                                           int kByte, void* lds, int w, int lane) {
#pragma unroll
  for (int j = 0; j < 2; j++) {
    const int base_off = (w << 11) + (j << 10);
    const int boff = base_off + (lane << 4);
    const int r = boff >> 6;
    const int s = (boff >> 4) & 3;
    const int cb = ((s ^ (r & 3)) << 4);
    const char* src = (const char*)gbase + (row0 + r) * rowStrideB + kByte + cb;
    __builtin_amdgcn_global_load_lds(
        (const __attribute__((address_space(1))) void*)src,
        (__attribute__((address_space(3))) void*)((char*)lds + base_off), 16, 0, 0);
  }
}

__global__ __launch_bounds__(256) void k_out(const bf16* __restrict__ xb,
                                             const bf16* __restrict__ WD,
                                             const bf16* __restrict__ Sb,
                                             const bf16* __restrict__ CW,
                                             const float* __restrict__ bias,
                                             float* __restrict__ out) {
  __shared__ bf16 As[2][128 * 32];
  __shared__ bf16 Bs[2][128 * 32];
  const int tid = threadIdx.x;
  const int w = tid >> 6, lane = tid & 63;
  const int swz = (blockIdx.x & 7) * 128 + (blockIdx.x >> 3);
  const int bm = swz >> 2, bn = swz & 3;
  const long rowbase = (long)bm * 128;
  const long colbase = (long)bn * 128;
  const int wr = w >> 1, wc = w & 1;
  const int l15 = lane & 15, kg = lane >> 4;
  const int kgs = kg ^ (l15 & 3);

  f32x4 acc[4][4];
#pragma unroll
  for (int m = 0; m < 4; m++)
#pragma unroll
    for (int n = 0; n < 4; n++) acc[m][n] = (f32x4)(0.0f);

  const int aoff = (wr * 64 + l15) * 32 + kgs * 8;
  const int boff = (wc * 64 + l15) * 32 + kgs * 8;

  auto STAGE = [&](int ti, int b) {
    if (ti < 16) {
      stage_tile(xb, rowbase, 1024, ti * 64, &As[b][0], w, lane);
      stage_tile(WD, colbase, 1024, ti * 64, &Bs[b][0], w, lane);
    } else {
      stage_tile(Sb, rowbase, 64, 0, &As[b][0], w, lane);
      stage_tile(CW, colbase, 64, 0, &Bs[b][0], w, lane);
    }
  };

  STAGE(0, 0);
  __syncthreads();
#pragma unroll 1
  for (int kt = 0; kt < 17; kt++) {
    const int cur = kt & 1;
    if (kt < 16) STAGE(kt + 1, cur ^ 1);
    bf16x8 af[4], bfr[4];
#pragma unroll
    for (int m = 0; m < 4; m++) af[m] = *(const bf16x8*)&As[cur][aoff + m * 16 * 32];
#pragma unroll
    for (int n = 0; n < 4; n++) bfr[n] = *(const bf16x8*)&Bs[cur][boff + n * 16 * 32];
#pragma unroll
    for (int m = 0; m < 4; m++)
#pragma unroll
      for (int n = 0; n < 4; n++)
        acc[m][n] = __builtin_amdgcn_mfma_f32_16x16x32_bf16(af[m], bfr[n], acc[m][n], 0, 0, 0);
    __syncthreads();
  }
#pragma unroll
  for (int n = 0; n < 4; n++) {
    const int e = (int)colbase + wc * 64 + n * 16 + l15;
    const float bv = bias[e];
#pragma unroll
    for (int m = 0; m < 4; m++) {
      const long r0 = rowbase + wr * 64 + m * 16 + kg * 4;
      const f32x4 v = acc[m][n];
#pragma unroll
      for (int jj = 0; jj < 4; jj++) out[(r0 + jj) * (long)D_MODEL + e] = v[jj] + bv;
    }
  }
}

extern "C" void kernel_launch(void* const* d_in, const int* in_sizes, int n_in,
                              void* d_out, int out_size, void* d_ws, size_t ws_size,
                              hipStream_t stream) {
  const float* x      = (const float*)d_in[0];
  const float* A      = (const float*)d_in[1];
  const float* B      = (const float*)d_in[2];
  const float* C      = (const float*)d_in[3];
  const float* Dv     = (const float*)d_in[4];
  const float* log_dt = (const float*)d_in[5];
  const float* W      = (const float*)d_in[6];
  const float* b_out  = (const float*)d_in[7];
  float* out = (float*)d_out;
  float* fs  = out + (long)MROWS * D_MODEL;  // final_state (8x32) after y

  char* ws = (char*)d_ws;
  float* A_bar = (float*)(ws + 0);                    // 4 KB
  bf16*  Bhi   = (bf16*)(ws + (4L << 10));            // 32 KB
  bf16*  Blo   = (bf16*)(ws + (36L << 10));           // 32 KB
  bf16*  CW    = (bf16*)(ws + (68L << 10));           // 32 KB
  bf16*  WD    = (bf16*)(ws + (100L << 10));          // 512 KB
  bf16*  Sb    = (bf16*)(ws + (612L << 10));          // 2 MB
  float* uB    = (float*)(ws + (2660L << 10));        // 4 MB
  bf16*  xb    = (bf16*)(ws + (6756L << 10));         // 32 MB   (total ~38.6 MB)
  int*   bar   = (int*)(ws + (48L << 20));            // grid-barrier counters

  hipMemsetAsync((void*)bar, 0, 256, stream);
  k_fused<<<dim3(NBLK), dim3(256), 0, stream>>>(x, A, B, C, Dv, log_dt, W, fs,
                                                A_bar, Bhi, Blo, CW, WD, Sb, uB, xb, bar);
  k_out<<<dim3((MROWS / 128) * (D_MODEL / 128)), dim3(256), 0, stream>>>(xb, WD, Sb, CW, b_out, out);
}

// Round 7
// 197.257 us; speedup vs baseline: 1.8621x; 1.8621x over previous
//
#include <hip/hip_runtime.h>
#include <hip/hip_bf16.h>

#define D_MODEL 512
#define D_STATE 32
#define BATCH 8
#define SEQ 4096
#define MROWS (BATCH * SEQ)
#define NBLK 1024

typedef __bf16 bf16;
typedef __bf16 bf16x4 __attribute__((ext_vector_type(4)));
typedef __bf16 bf16x8 __attribute__((ext_vector_type(8)));
typedef float f32x4 __attribute__((ext_vector_type(4)));

struct PreS { float sM[32][32]; float sX[32][32]; float red[256]; float sdt; };
union SMemF {
  PreS pre;
  bf16 xt[32][520];   // padded row (1040 B): conflict-free b128 frag reads
  float scan[64];
};                     // 33280 B -> 4 blocks/CU

// ---------------- hierarchical grid barrier ----------------
// bar layout (ints): [g*32] g=0..31 per-group counters (128 B apart),
// [32*32] global counter, [33*32] release flag, [34*32] pre-flag.
// All zeroed by hipMemsetAsync before launch. Spin on read-only flag line.
__device__ __forceinline__ void gridbar(int* bar) {
  __syncthreads();
  if (threadIdx.x == 0) {
    __threadfence();  // writeback: make this block's prior stores LLC-visible
    const int grp = blockIdx.x & 31;
    if (__hip_atomic_fetch_add(bar + grp * 32, 1, __ATOMIC_ACQ_REL,
                               __HIP_MEMORY_SCOPE_AGENT) == (NBLK / 32) - 1) {
      if (__hip_atomic_fetch_add(bar + 32 * 32, 1, __ATOMIC_ACQ_REL,
                                 __HIP_MEMORY_SCOPE_AGENT) == 31) {
        __hip_atomic_store(bar + 33 * 32, 1, __ATOMIC_RELEASE, __HIP_MEMORY_SCOPE_AGENT);
      }
    }
    int it = 0;
    while (__hip_atomic_load(bar + 33 * 32, __ATOMIC_RELAXED, __HIP_MEMORY_SCOPE_AGENT) == 0) {
      __builtin_amdgcn_s_sleep(32);
      if (++it > (1 << 20)) break;  // failsafe: never hang
    }
    __threadfence();  // acquire: invalidate stale caches
  }
  __syncthreads();
}

#define CHUNK 16
#define BURN 80
#define NCHUNK (SEQ / CHUNK)   // 256 chunks per batch, 2048 chains

// ========== fused: [pre | convert+CW+WD] -> per-block uB MFMA -> gridbar -> scan ==========
__global__ __launch_bounds__(256, 4) void k_fused(
    const float* __restrict__ x, const float* __restrict__ A, const float* __restrict__ B,
    const float* __restrict__ C, const float* __restrict__ Dv, const float* __restrict__ log_dt,
    const float* __restrict__ W, float* __restrict__ fs,
    float* __restrict__ A_bar, bf16* __restrict__ Bhi, bf16* __restrict__ Blo,
    bf16* __restrict__ CW, bf16* __restrict__ WD, bf16* __restrict__ Sb,
    float* __restrict__ uB, bf16* __restrict__ xb, int* __restrict__ bar) {
  __shared__ SMemF sm;
  const int bid = blockIdx.x, t = threadIdx.x;
  const int w = t >> 6, lane = t & 63;
  const int l15 = lane & 15, kg = lane >> 4;
  int* preflag = bar + 34 * 32;

  // ---- block 0: precompute FIRST (dt, X=(I-.5dtA)^-1, A_bar, packed Bhi/Blo), then flag
  if (bid == 0) {
    auto& P = sm.pre;
    float p = 0.f;
    for (int i = t; i < D_MODEL; i += 256) {
      float v = __expf(log_dt[i]);
      v = fminf(fmaxf(v, 1e-4f), 1.0f);
      p += v;
    }
    P.red[t] = p;
    __syncthreads();
    for (int s2 = 128; s2 > 0; s2 >>= 1) {
      if (t < s2) P.red[t] += P.red[t + s2];
      __syncthreads();
    }
    if (t == 0) P.sdt = P.red[0] * (1.0f / D_MODEL);
    __syncthreads();
    const float dt = P.sdt;
    for (int i = t; i < 1024; i += 256) {
      int r = i >> 5, c = i & 31;
      P.sM[r][c] = (r == c ? 1.f : 0.f) - 0.5f * dt * A[i];
    }
    __syncthreads();
    if (t < 32) {   // forward substitution (M lower-tri, diag >= 1)
      const int j = t;
      float xcol[32];
#pragma unroll
      for (int i = 0; i < 32; i++) {
        float sacc = 0.f;
#pragma unroll
        for (int k = 0; k < 32; k++) {
          if (k < i) sacc -= P.sM[i][k] * xcol[k];
        }
        float num = (i == j ? 1.f : 0.f) + sacc;
        xcol[i] = (i >= j) ? num / P.sM[i][i] : 0.f;
      }
      for (int i = 0; i < 32; i++) P.sX[i][j] = xcol[i];
    }
    __syncthreads();
    for (int i = t; i < 1024; i += 256) {   // A_bar = (I + 0.5dt A) @ X
      int r = i >> 5, c = i & 31;
      float s = 0.f;
      for (int k = 0; k < 32; k++) {
        float p2 = (r == k ? 1.f : 0.f) + 0.5f * dt * A[r * 32 + k];
        s += p2 * P.sX[k][c];
      }
      A_bar[i] = s;
    }
    // packed B_bar = dt * X @ B, hi/lo split; thread t owns column k (coalesced)
#pragma unroll 1
    for (int q = 0; q < 2; q++) {
      const int k = q * 256 + t;
      float bcol[32];
#pragma unroll
      for (int kk = 0; kk < 32; kk++) bcol[kk] = B[kk * D_MODEL + k];
      const int kt = k >> 5, kg2 = (k >> 3) & 3, j = k & 7;
#pragma unroll 1
      for (int n = 0; n < 32; n++) {
        float s = 0.f;
#pragma unroll
        for (int kk = 0; kk < 32; kk++) s = fmaf(P.sX[n][kk], bcol[kk], s);
        s *= dt;
        const bf16 hi = (bf16)s;
        const float lo = s - (float)hi;
        const int pidx = ((kt * 4 + kg2) * 32 + n) * 8 + j;
        Bhi[pidx] = hi;
        Blo[pidx] = (bf16)lo;
      }
    }
    __syncthreads();
    if (t == 0) {
      __threadfence();
      __hip_atomic_store(preflag, 1, __ATOMIC_RELEASE, __HIP_MEMORY_SCOPE_AGENT);
    }
    __syncthreads();  // sm.pre dead; safe to reuse as sm.xt below
  }

  // ---- all blocks: convert own 32 rows x -> xb (global) + LDS bf16 tile ----
  {
    const long rowbase = (long)bid * 32;
    const int r = t >> 3, cq = (t & 7) * 4;
    const float* xp = x + (rowbase + r) * D_MODEL + cq;
    bf16* xo = xb + (rowbase + r) * D_MODEL + cq;
#pragma unroll
    for (int kt = 0; kt < 16; kt++) {
      const f32x4 v = *(const f32x4*)(xp + kt * 32);
      bf16x4 h;
      h[0] = (bf16)v[0]; h[1] = (bf16)v[1]; h[2] = (bf16)v[2]; h[3] = (bf16)v[3];
      *(bf16x4*)(xo + kt * 32) = h;
      *(bf16x4*)&sm.xt[r][kt * 32 + cq] = h;
    }
  }
  // ---- side jobs (independent of pre): CW (blocks 1..64), WD (65..80) ----
  if (bid >= 1 && bid <= 64) {
    const int idx = (bid - 1) * 256 + t;
    const int e = idx >> 5, n = idx & 31;
    float s = 0.f;
    for (int d = 0; d < D_MODEL; d += 4) {
      const f32x4 wv = *(const f32x4*)(W + e * D_MODEL + d);
      s = fmaf(wv[0], C[(d + 0) * D_STATE + n], s);
      s = fmaf(wv[1], C[(d + 1) * D_STATE + n], s);
      s = fmaf(wv[2], C[(d + 2) * D_STATE + n], s);
      s = fmaf(wv[3], C[(d + 3) * D_STATE + n], s);
    }
    CW[idx] = (bf16)s;
  } else if (bid >= 65 && bid <= 80) {
#pragma unroll
    for (int jj = 0; jj < 16; jj++) {
      const int i = (bid - 65) * 16384 + jj * 1024 + t * 4;
      const f32x4 wv = *(const f32x4*)(W + i);
      const f32x4 dv = *(const f32x4*)(Dv + (i & 511));
      bf16x4 h;
#pragma unroll
      for (int q = 0; q < 4; q++) h[q] = (bf16)(wv[q] * dv[q]);
      *(bf16x4*)(WD + i) = h;
    }
  }
  // ---- wait for pre-flag (block 0 already set it), then own-tile uB MFMA ----
  if (bid != 0) {
    if (t == 0) {
      int it = 0;
      while (__hip_atomic_load(preflag, __ATOMIC_RELAXED, __HIP_MEMORY_SCOPE_AGENT) == 0) {
        __builtin_amdgcn_s_sleep(8);
        if (++it > (1 << 20)) break;
      }
      __threadfence();
    }
  }
  __syncthreads();   // LDS tile complete + Bhi/Blo visible
  {
    const int m = w & 1, n = w >> 1;   // wave -> (row-frag, col-frag)
    f32x4 acc = (f32x4)(0.0f);
#pragma unroll
    for (int kt = 0; kt < 16; kt++) {
      const bf16x8 af = *(const bf16x8*)&sm.xt[m * 16 + l15][kt * 32 + kg * 8];
      const int bo = ((kt * 4 + kg) * 32 + l15) * 8 + n * 128;
      const bf16x8 bh = *(const bf16x8*)(Bhi + bo);
      const bf16x8 bl = *(const bf16x8*)(Blo + bo);
      acc = __builtin_amdgcn_mfma_f32_16x16x32_bf16(af, bh, acc, 0, 0, 0);
      acc = __builtin_amdgcn_mfma_f32_16x16x32_bf16(af, bl, acc, 0, 0, 0);
    }
    const long r0 = (long)bid * 32 + m * 16 + kg * 4;
#pragma unroll
    for (int jj = 0; jj < 4; jj++)
      uB[(r0 + jj) * D_STATE + n * 16 + l15] = acc[jj];
  }

  gridbar(bar);

  // ---------------- scan: 2 chains per block (1 wave active) ----------------
  if (t < 64) {
    const int g = t >> 5, n = t & 31;
    const int chain = bid * 2 + g;
    const int b = chain >> 8;
    const int ch = chain & 255;
    const int cs = ch * CHUNK;
    const int t0 = cs - BURN;
    const int ce = cs + CHUNK;

    float a[32];
#pragma unroll
    for (int k = 0; k < 32; k += 4) {
      const f32x4 v = *(const f32x4*)(A_bar + n * 32 + k);
      a[k] = v[0]; a[k + 1] = v[1]; a[k + 2] = v[2]; a[k + 3] = v[3];
    }
    const float* ub = uB + (long)b * SEQ * D_STATE + n;
    bf16* sp = Sb + ((long)b * SEQ + cs) * D_STATE + n;
    float* myslot = &sm.scan[g * 32];

    float s = 0.f;
    float ubuf[8], unext[8];
#pragma unroll
    for (int i = 0; i < 8; i++) {
      const int tt = t0 + i;
      ubuf[i] = (tt >= 0) ? ub[(long)tt * D_STATE] : 0.f;
    }
    for (int tg = t0; tg < ce; tg += 8) {
      const int tn = tg + 8;
#pragma unroll
      for (int i = 0; i < 8; i++) {
        const int tt = tn + i;
        unext[i] = (tt >= 0 && tt < ce) ? ub[(long)tt * D_STATE] : 0.f;
      }
#pragma unroll
      for (int i = 0; i < 8; i++) {
        const int tt = tg + i;
        myslot[n] = s;   // ds_write_b32, wave-ordered before the reads below
        const f32x4 s0 = *(const f32x4*)(myslot + 0);
        const f32x4 s1 = *(const f32x4*)(myslot + 4);
        const f32x4 s2 = *(const f32x4*)(myslot + 8);
        const f32x4 s3 = *(const f32x4*)(myslot + 12);
        const f32x4 s4 = *(const f32x4*)(myslot + 16);
        const f32x4 s5 = *(const f32x4*)(myslot + 20);
        const f32x4 s6 = *(const f32x4*)(myslot + 24);
        const f32x4 s7 = *(const f32x4*)(myslot + 28);
        float acc0 = ubuf[i], acc1 = 0.f, acc2 = 0.f, acc3 = 0.f;
#pragma unroll
        for (int q = 0; q < 4; q++) {
          acc0 = fmaf(a[0 + q],  s0[q], acc0);
          acc1 = fmaf(a[4 + q],  s1[q], acc1);
          acc2 = fmaf(a[8 + q],  s2[q], acc2);
          acc3 = fmaf(a[12 + q], s3[q], acc3);
          acc0 = fmaf(a[16 + q], s4[q], acc0);
          acc1 = fmaf(a[20 + q], s5[q], acc1);
          acc2 = fmaf(a[24 + q], s6[q], acc2);
          acc3 = fmaf(a[28 + q], s7[q], acc3);
        }
        const float z = (acc0 + acc1) + (acc2 + acc3);
        const float e = __expf(2.f * z);
        const float r = __builtin_amdgcn_rcpf(e + 1.f);
        s = fmaf(-2.f, r, 1.f);
        if (tt >= cs) sp[(long)(tt - cs) * D_STATE] = (bf16)s;
      }
#pragma unroll
      for (int i = 0; i < 8; i++) ubuf[i] = unext[i];
    }
    if (ch == NCHUNK - 1) fs[b * D_STATE + n] = s;
  }
}

// ---------------- k_out: out = S@CW^T + xb@WD^T + b (bf16 MFMA, 128x128 tile) ----------------
__device__ __forceinline__ void stage_tile(const void* gbase, long row0, long rowStrideB,
                                           int kByte, void* lds, int w, int lane) {
#pragma unroll
  for (int j = 0; j < 2; j++) {
    const int base_off = (w << 11) + (j << 10);
    const int boff = base_off + (lane << 4);
    const int r = boff >> 6;
    const int s = (boff >> 4) & 3;
    const int cb = ((s ^ (r & 3)) << 4);
    const char* src = (const char*)gbase + (row0 + r) * rowStrideB + kByte + cb;
    __builtin_amdgcn_global_load_lds(
        (const __attribute__((address_space(1))) void*)src,
        (__attribute__((address_space(3))) void*)((char*)lds + base_off), 16, 0, 0);
  }
}

__global__ __launch_bounds__(256) void k_out(const bf16* __restrict__ xb,
                                             const bf16* __restrict__ WD,
                                             const bf16* __restrict__ Sb,
                                             const bf16* __restrict__ CW,
                                             const float* __restrict__ bias,
                                             float* __restrict__ out) {
  __shared__ bf16 As[2][128 * 32];
  __shared__ bf16 Bs[2][128 * 32];
  const int tid = threadIdx.x;
  const int w = tid >> 6, lane = tid & 63;
  const int swz = (blockIdx.x & 7) * 128 + (blockIdx.x >> 3);
  const int bm = swz >> 2, bn = swz & 3;
  const long rowbase = (long)bm * 128;
  const long colbase = (long)bn * 128;
  const int wr = w >> 1, wc = w & 1;
  const int l15 = lane & 15, kg = lane >> 4;
  const int kgs = kg ^ (l15 & 3);

  f32x4 acc[4][4];
#pragma unroll
  for (int m = 0; m < 4; m++)
#pragma unroll
    for (int n = 0; n < 4; n++) acc[m][n] = (f32x4)(0.0f);

  const int aoff = (wr * 64 + l15) * 32 + kgs * 8;
  const int boff = (wc * 64 + l15) * 32 + kgs * 8;

  auto STAGE = [&](int ti, int b) {
    if (ti < 16) {
      stage_tile(xb, rowbase, 1024, ti * 64, &As[b][0], w, lane);
      stage_tile(WD, colbase, 1024, ti * 64, &Bs[b][0], w, lane);
    } else {
      stage_tile(Sb, rowbase, 64, 0, &As[b][0], w, lane);
      stage_tile(CW, colbase, 64, 0, &Bs[b][0], w, lane);
    }
  };

  STAGE(0, 0);
  __syncthreads();
#pragma unroll 1
  for (int kt = 0; kt < 17; kt++) {
    const int cur = kt & 1;
    if (kt < 16) STAGE(kt + 1, cur ^ 1);
    bf16x8 af[4], bfr[4];
#pragma unroll
    for (int m = 0; m < 4; m++) af[m] = *(const bf16x8*)&As[cur][aoff + m * 16 * 32];
#pragma unroll
    for (int n = 0; n < 4; n++) bfr[n] = *(const bf16x8*)&Bs[cur][boff + n * 16 * 32];
#pragma unroll
    for (int m = 0; m < 4; m++)
#pragma unroll
      for (int n = 0; n < 4; n++)
        acc[m][n] = __builtin_amdgcn_mfma_f32_16x16x32_bf16(af[m], bfr[n], acc[m][n], 0, 0, 0);
    __syncthreads();
  }
#pragma unroll
  for (int n = 0; n < 4; n++) {
    const int e = (int)colbase + wc * 64 + n * 16 + l15;
    const float bv = bias[e];
#pragma unroll
    for (int m = 0; m < 4; m++) {
      const long r0 = rowbase + wr * 64 + m * 16 + kg * 4;
      const f32x4 v = acc[m][n];
#pragma unroll
      for (int jj = 0; jj < 4; jj++) out[(r0 + jj) * (long)D_MODEL + e] = v[jj] + bv;
    }
  }
}

extern "C" void kernel_launch(void* const* d_in, const int* in_sizes, int n_in,
                              void* d_out, int out_size, void* d_ws, size_t ws_size,
                              hipStream_t stream) {
  const float* x      = (const float*)d_in[0];
  const float* A      = (const float*)d_in[1];
  const float* B      = (const float*)d_in[2];
  const float* C      = (const float*)d_in[3];
  const float* Dv     = (const float*)d_in[4];
  const float* log_dt = (const float*)d_in[5];
  const float* W      = (const float*)d_in[6];
  const float* b_out  = (const float*)d_in[7];
  float* out = (float*)d_out;
  float* fs  = out + (long)MROWS * D_MODEL;  // final_state (8x32) after y

  char* ws = (char*)d_ws;
  float* A_bar = (float*)(ws + 0);                    // 4 KB
  bf16*  Bhi   = (bf16*)(ws + (4L << 10));            // 32 KB
  bf16*  Blo   = (bf16*)(ws + (36L << 10));           // 32 KB
  bf16*  CW    = (bf16*)(ws + (68L << 10));           // 32 KB
  bf16*  WD    = (bf16*)(ws + (100L << 10));          // 512 KB
  bf16*  Sb    = (bf16*)(ws + (612L << 10));          // 2 MB
  float* uB    = (float*)(ws + (2660L << 10));        // 4 MB
  bf16*  xb    = (bf16*)(ws + (6756L << 10));         // 32 MB
  int*   bar   = (int*)(ws + (48L << 20));            // barrier counters + flags

  hipMemsetAsync((void*)bar, 0, 8192, stream);
  k_fused<<<dim3(NBLK), dim3(256), 0, stream>>>(x, A, B, C, Dv, log_dt, W, fs,
                                                A_bar, Bhi, Blo, CW, WD, Sb, uB, xb, bar);
  k_out<<<dim3((MROWS / 128) * (D_MODEL / 128)), dim3(256), 0, stream>>>(xb, WD, Sb, CW, b_out, out);
}

// Round 8
// 130.464 us; speedup vs baseline: 2.8155x; 1.5120x over previous
//
#include <hip/hip_runtime.h>
#include <hip/hip_bf16.h>

#define D_MODEL 512
#define D_STATE 32
#define BATCH 8
#define SEQ 4096
#define MROWS (BATCH * SEQ)
#define NBLK 1024

typedef __bf16 bf16;
typedef __bf16 bf16x4 __attribute__((ext_vector_type(4)));
typedef __bf16 bf16x8 __attribute__((ext_vector_type(8)));
typedef float f32x4 __attribute__((ext_vector_type(4)));

struct PreS { float sM[32][32]; float sX[32][32]; float red[256]; float sdt; };
union SMemF {
  PreS pre;
  bf16 xt[32][520];   // padded row (1040 B): conflict-free b128 frag reads
};                     // 33280 B -> 4 blocks/CU

#define CHUNK 16
#define BURN 80
#define NCHUNK (SEQ / CHUNK)   // 256 chunks per batch, 2048 chains

// ========== k_A: [pre(b0)+preflag | convert+CW+WD] -> per-block uB MFMA ==========
__global__ __launch_bounds__(256, 4) void k_A(
    const float* __restrict__ x, const float* __restrict__ A, const float* __restrict__ B,
    const float* __restrict__ C, const float* __restrict__ Dv, const float* __restrict__ log_dt,
    const float* __restrict__ W,
    float* __restrict__ A_bar, bf16* __restrict__ Bhi, bf16* __restrict__ Blo,
    bf16* __restrict__ CW, bf16* __restrict__ WD,
    float* __restrict__ uB, bf16* __restrict__ xb, int* __restrict__ bar) {
  __shared__ SMemF sm;
  const int bid = blockIdx.x, t = threadIdx.x;
  const int w = t >> 6, lane = t & 63;
  const int l15 = lane & 15, kg = lane >> 4;
  int* preflag = bar + 34 * 32;

  // ---- block 0: precompute FIRST (dt, X=(I-.5dtA)^-1, A_bar, packed Bhi/Blo), then flag
  if (bid == 0) {
    auto& P = sm.pre;
    float p = 0.f;
    for (int i = t; i < D_MODEL; i += 256) {
      float v = __expf(log_dt[i]);
      v = fminf(fmaxf(v, 1e-4f), 1.0f);
      p += v;
    }
    P.red[t] = p;
    __syncthreads();
    for (int s2 = 128; s2 > 0; s2 >>= 1) {
      if (t < s2) P.red[t] += P.red[t + s2];
      __syncthreads();
    }
    if (t == 0) P.sdt = P.red[0] * (1.0f / D_MODEL);
    __syncthreads();
    const float dt = P.sdt;
    for (int i = t; i < 1024; i += 256) {
      int r = i >> 5, c = i & 31;
      P.sM[r][c] = (r == c ? 1.f : 0.f) - 0.5f * dt * A[i];
    }
    __syncthreads();
    if (t < 32) {   // forward substitution (M lower-tri, diag >= 1)
      const int j = t;
      float xcol[32];
#pragma unroll
      for (int i = 0; i < 32; i++) {
        float sacc = 0.f;
#pragma unroll
        for (int k = 0; k < 32; k++) {
          if (k < i) sacc -= P.sM[i][k] * xcol[k];
        }
        float num = (i == j ? 1.f : 0.f) + sacc;
        xcol[i] = (i >= j) ? num / P.sM[i][i] : 0.f;
      }
      for (int i = 0; i < 32; i++) P.sX[i][j] = xcol[i];
    }
    __syncthreads();
    for (int i = t; i < 1024; i += 256) {   // A_bar = (I + 0.5dt A) @ X
      int r = i >> 5, c = i & 31;
      float s = 0.f;
      for (int k = 0; k < 32; k++) {
        float p2 = (r == k ? 1.f : 0.f) + 0.5f * dt * A[r * 32 + k];
        s += p2 * P.sX[k][c];
      }
      A_bar[i] = s;
    }
    // packed B_bar = dt * X @ B, hi/lo split; thread t owns column k (coalesced)
#pragma unroll 1
    for (int q = 0; q < 2; q++) {
      const int k = q * 256 + t;
      float bcol[32];
#pragma unroll
      for (int kk = 0; kk < 32; kk++) bcol[kk] = B[kk * D_MODEL + k];
      const int kt = k >> 5, kg2 = (k >> 3) & 3, j = k & 7;
#pragma unroll 1
      for (int n = 0; n < 32; n++) {
        float s = 0.f;
#pragma unroll
        for (int kk = 0; kk < 32; kk++) s = fmaf(P.sX[n][kk], bcol[kk], s);
        s *= dt;
        const bf16 hi = (bf16)s;
        const float lo = s - (float)hi;
        const int pidx = ((kt * 4 + kg2) * 32 + n) * 8 + j;
        Bhi[pidx] = hi;
        Blo[pidx] = (bf16)lo;
      }
    }
    __syncthreads();
    if (t == 0) {
      __threadfence();
      __hip_atomic_store(preflag, 1, __ATOMIC_RELEASE, __HIP_MEMORY_SCOPE_AGENT);
    }
    __syncthreads();  // sm.pre dead; safe to reuse as sm.xt below
  }

  // ---- all blocks: convert own 32 rows x -> xb (global) + LDS bf16 tile ----
  {
    const long rowbase = (long)bid * 32;
    const int r = t >> 3, cq = (t & 7) * 4;
    const float* xp = x + (rowbase + r) * D_MODEL + cq;
    bf16* xo = xb + (rowbase + r) * D_MODEL + cq;
#pragma unroll
    for (int kt = 0; kt < 16; kt++) {
      const f32x4 v = *(const f32x4*)(xp + kt * 32);
      bf16x4 h;
      h[0] = (bf16)v[0]; h[1] = (bf16)v[1]; h[2] = (bf16)v[2]; h[3] = (bf16)v[3];
      *(bf16x4*)(xo + kt * 32) = h;
      *(bf16x4*)&sm.xt[r][kt * 32 + cq] = h;
    }
  }
  // ---- side jobs (independent of pre): CW (blocks 1..64), WD (65..80) ----
  if (bid >= 1 && bid <= 64) {
    const int idx = (bid - 1) * 256 + t;
    const int e = idx >> 5, n = idx & 31;
    float s = 0.f;
    for (int d = 0; d < D_MODEL; d += 4) {
      const f32x4 wv = *(const f32x4*)(W + e * D_MODEL + d);
      s = fmaf(wv[0], C[(d + 0) * D_STATE + n], s);
      s = fmaf(wv[1], C[(d + 1) * D_STATE + n], s);
      s = fmaf(wv[2], C[(d + 2) * D_STATE + n], s);
      s = fmaf(wv[3], C[(d + 3) * D_STATE + n], s);
    }
    CW[idx] = (bf16)s;
  } else if (bid >= 65 && bid <= 80) {
#pragma unroll
    for (int jj = 0; jj < 16; jj++) {
      const int i = (bid - 65) * 16384 + jj * 1024 + t * 4;
      const f32x4 wv = *(const f32x4*)(W + i);
      const f32x4 dv = *(const f32x4*)(Dv + (i & 511));
      bf16x4 h;
#pragma unroll
      for (int q = 0; q < 4; q++) h[q] = (bf16)(wv[q] * dv[q]);
      *(bf16x4*)(WD + i) = h;
    }
  }
  // ---- wait for pre-flag (one-way producer flag; no RMW storm), then uB MFMA ----
  if (bid != 0) {
    if (t == 0) {
      int it = 0;
      while (__hip_atomic_load(preflag, __ATOMIC_RELAXED, __HIP_MEMORY_SCOPE_AGENT) == 0) {
        __builtin_amdgcn_s_sleep(8);
        if (++it > (1 << 20)) break;
      }
      __threadfence();
    }
  }
  __syncthreads();   // LDS tile complete + Bhi/Blo visible
  {
    const int m = w & 1, n = w >> 1;   // wave -> (row-frag, col-frag)
    f32x4 acc = (f32x4)(0.0f);
#pragma unroll
    for (int kt = 0; kt < 16; kt++) {
      const bf16x8 af = *(const bf16x8*)&sm.xt[m * 16 + l15][kt * 32 + kg * 8];
      const int bo = ((kt * 4 + kg) * 32 + l15) * 8 + n * 128;
      const bf16x8 bh = *(const bf16x8*)(Bhi + bo);
      const bf16x8 bl = *(const bf16x8*)(Blo + bo);
      acc = __builtin_amdgcn_mfma_f32_16x16x32_bf16(af, bh, acc, 0, 0, 0);
      acc = __builtin_amdgcn_mfma_f32_16x16x32_bf16(af, bl, acc, 0, 0, 0);
    }
    const long r0 = (long)bid * 32 + m * 16 + kg * 4;
#pragma unroll
    for (int jj = 0; jj < 4; jj++)
      uB[(r0 + jj) * D_STATE + n * 16 + l15] = acc[jj];
  }
}

// ---------------- k_scan: standalone; a[] pinned in VGPRs (no remat/reload) ----------------
__global__ void k_scan(const float* __restrict__ uB, const float* __restrict__ A_bar,
                       bf16* __restrict__ Sb, float* __restrict__ fs) {
  __shared__ float sbuf[256];         // 8 groups x 32 state elems
  const int t = threadIdx.x;
  const int g = t >> 5, n = t & 31;
  const int chain = blockIdx.x * 8 + g;
  const int b = chain >> 8;           // 256 chunks per batch
  const int ch = chain & 255;
  const int cs = ch * CHUNK;
  const int t0 = cs - BURN;           // may be negative (u treated as 0 there)
  const int ce = cs + CHUNK;

  float a[32];
#pragma unroll
  for (int k = 0; k < 32; k += 4) {
    const f32x4 v = *(const f32x4*)(A_bar + n * 32 + k);
    a[k] = v[0]; a[k + 1] = v[1]; a[k + 2] = v[2]; a[k + 3] = v[3];
  }
  // Pin: opaque values cannot be rematerialized as global re-loads inside the
  // serial loop (VGPR_Count=48..56 in prior rounds => compiler was re-loading
  // A_bar on the critical path every step).
#pragma unroll
  for (int k = 0; k < 32; k++) asm volatile("" : "+v"(a[k]));

  const float* ub = uB + (long)b * SEQ * D_STATE + n;
  bf16* sp = Sb + ((long)b * SEQ + cs) * D_STATE + n;
  float* myslot = &sbuf[g * 32];

  float s = 0.f;
  float ubuf[8], unext[8];
#pragma unroll
  for (int i = 0; i < 8; i++) {
    const int tt = t0 + i;
    ubuf[i] = (tt >= 0) ? ub[(long)tt * D_STATE] : 0.f;
  }
  for (int tg = t0; tg < ce; tg += 8) {
    const int tn = tg + 8;
#pragma unroll
    for (int i = 0; i < 8; i++) {
      const int tt = tn + i;
      unext[i] = (tt >= 0 && tt < ce) ? ub[(long)tt * D_STATE] : 0.f;
    }
#pragma unroll
    for (int i = 0; i < 8; i++) {
      const int tt = tg + i;
      myslot[n] = s;   // ds_write_b32, wave-ordered before the reads below
      const f32x4 s0 = *(const f32x4*)(myslot + 0);
      const f32x4 s1 = *(const f32x4*)(myslot + 4);
      const f32x4 s2 = *(const f32x4*)(myslot + 8);
      const f32x4 s3 = *(const f32x4*)(myslot + 12);
      const f32x4 s4 = *(const f32x4*)(myslot + 16);
      const f32x4 s5 = *(const f32x4*)(myslot + 20);
      const f32x4 s6 = *(const f32x4*)(myslot + 24);
      const f32x4 s7 = *(const f32x4*)(myslot + 28);
      float acc0 = ubuf[i], acc1 = 0.f, acc2 = 0.f, acc3 = 0.f;
#pragma unroll
      for (int q = 0; q < 4; q++) {
        acc0 = fmaf(a[0 + q],  s0[q], acc0);
        acc1 = fmaf(a[4 + q],  s1[q], acc1);
        acc2 = fmaf(a[8 + q],  s2[q], acc2);
        acc3 = fmaf(a[12 + q], s3[q], acc3);
        acc0 = fmaf(a[16 + q], s4[q], acc0);
        acc1 = fmaf(a[20 + q], s5[q], acc1);
        acc2 = fmaf(a[24 + q], s6[q], acc2);
        acc3 = fmaf(a[28 + q], s7[q], acc3);
      }
      const float z = (acc0 + acc1) + (acc2 + acc3);
      const float e = __expf(2.f * z);
      const float r = __builtin_amdgcn_rcpf(e + 1.f);
      s = fmaf(-2.f, r, 1.f);
      if (tt >= cs) sp[(long)(tt - cs) * D_STATE] = (bf16)s;
    }
#pragma unroll
    for (int i = 0; i < 8; i++) ubuf[i] = unext[i];
  }
  if (ch == NCHUNK - 1) fs[b * D_STATE + n] = s;
}

// ---------------- k_out: out = S@CW^T + xb@WD^T + b (bf16 MFMA, 128x128 tile) ----------------
__device__ __forceinline__ void stage_tile(const void* gbase, long row0, long rowStrideB,
                                           int kByte, void* lds, int w, int lane) {
#pragma unroll
  for (int j = 0; j < 2; j++) {
    const int base_off = (w << 11) + (j << 10);
    const int boff = base_off + (lane << 4);
    const int r = boff >> 6;
    const int s = (boff >> 4) & 3;
    const int cb = ((s ^ (r & 3)) << 4);
    const char* src = (const char*)gbase + (row0 + r) * rowStrideB + kByte + cb;
    __builtin_amdgcn_global_load_lds(
        (const __attribute__((address_space(1))) void*)src,
        (__attribute__((address_space(3))) void*)((char*)lds + base_off), 16, 0, 0);
  }
}

__global__ __launch_bounds__(256) void k_out(const bf16* __restrict__ xb,
                                             const bf16* __restrict__ WD,
                                             const bf16* __restrict__ Sb,
                                             const bf16* __restrict__ CW,
                                             const float* __restrict__ bias,
                                             float* __restrict__ out) {
  __shared__ bf16 As[2][128 * 32];
  __shared__ bf16 Bs[2][128 * 32];
  const int tid = threadIdx.x;
  const int w = tid >> 6, lane = tid & 63;
  const int swz = (blockIdx.x & 7) * 128 + (blockIdx.x >> 3);
  const int bm = swz >> 2, bn = swz & 3;
  const long rowbase = (long)bm * 128;
  const long colbase = (long)bn * 128;
  const int wr = w >> 1, wc = w & 1;
  const int l15 = lane & 15, kg = lane >> 4;
  const int kgs = kg ^ (l15 & 3);

  f32x4 acc[4][4];
#pragma unroll
  for (int m = 0; m < 4; m++)
#pragma unroll
    for (int n = 0; n < 4; n++) acc[m][n] = (f32x4)(0.0f);

  const int aoff = (wr * 64 + l15) * 32 + kgs * 8;
  const int boff = (wc * 64 + l15) * 32 + kgs * 8;

  auto STAGE = [&](int ti, int b) {
    if (ti < 16) {
      stage_tile(xb, rowbase, 1024, ti * 64, &As[b][0], w, lane);
      stage_tile(WD, colbase, 1024, ti * 64, &Bs[b][0], w, lane);
    } else {
      stage_tile(Sb, rowbase, 64, 0, &As[b][0], w, lane);
      stage_tile(CW, colbase, 64, 0, &Bs[b][0], w, lane);
    }
  };

  STAGE(0, 0);
  __syncthreads();
#pragma unroll 1
  for (int kt = 0; kt < 17; kt++) {
    const int cur = kt & 1;
    if (kt < 16) STAGE(kt + 1, cur ^ 1);
    bf16x8 af[4], bfr[4];
#pragma unroll
    for (int m = 0; m < 4; m++) af[m] = *(const bf16x8*)&As[cur][aoff + m * 16 * 32];
#pragma unroll
    for (int n = 0; n < 4; n++) bfr[n] = *(const bf16x8*)&Bs[cur][boff + n * 16 * 32];
#pragma unroll
    for (int m = 0; m < 4; m++)
#pragma unroll
      for (int n = 0; n < 4; n++)
        acc[m][n] = __builtin_amdgcn_mfma_f32_16x16x32_bf16(af[m], bfr[n], acc[m][n], 0, 0, 0);
    __syncthreads();
  }
#pragma unroll
  for (int n = 0; n < 4; n++) {
    const int e = (int)colbase + wc * 64 + n * 16 + l15;
    const float bv = bias[e];
#pragma unroll
    for (int m = 0; m < 4; m++) {
      const long r0 = rowbase + wr * 64 + m * 16 + kg * 4;
      const f32x4 v = acc[m][n];
#pragma unroll
      for (int jj = 0; jj < 4; jj++) out[(r0 + jj) * (long)D_MODEL + e] = v[jj] + bv;
    }
  }
}

extern "C" void kernel_launch(void* const* d_in, const int* in_sizes, int n_in,
                              void* d_out, int out_size, void* d_ws, size_t ws_size,
                              hipStream_t stream) {
  const float* x      = (const float*)d_in[0];
  const float* A      = (const float*)d_in[1];
  const float* B      = (const float*)d_in[2];
  const float* C      = (const float*)d_in[3];
  const float* Dv     = (const float*)d_in[4];
  const float* log_dt = (const float*)d_in[5];
  const float* W      = (const float*)d_in[6];
  const float* b_out  = (const float*)d_in[7];
  float* out = (float*)d_out;
  float* fs  = out + (long)MROWS * D_MODEL;  // final_state (8x32) after y

  char* ws = (char*)d_ws;
  float* A_bar = (float*)(ws + 0);                    // 4 KB
  bf16*  Bhi   = (bf16*)(ws + (4L << 10));            // 32 KB
  bf16*  Blo   = (bf16*)(ws + (36L << 10));           // 32 KB
  bf16*  CW    = (bf16*)(ws + (68L << 10));           // 32 KB
  bf16*  WD    = (bf16*)(ws + (100L << 10));          // 512 KB
  bf16*  Sb    = (bf16*)(ws + (612L << 10));          // 2 MB
  float* uB    = (float*)(ws + (2660L << 10));        // 4 MB
  bf16*  xb    = (bf16*)(ws + (6756L << 10));         // 32 MB
  int*   bar   = (int*)(ws + (48L << 20));            // preflag line

  hipMemsetAsync((void*)bar, 0, 8192, stream);
  k_A<<<dim3(NBLK), dim3(256), 0, stream>>>(x, A, B, C, Dv, log_dt, W,
                                            A_bar, Bhi, Blo, CW, WD, uB, xb, bar);
  k_scan<<<dim3(256), dim3(256), 0, stream>>>(uB, A_bar, Sb, fs);
  k_out<<<dim3((MROWS / 128) * (D_MODEL / 128)), dim3(256), 0, stream>>>(xb, WD, Sb, CW, b_out, out);
}

// Round 9
// 93.539 us; speedup vs baseline: 3.9269x; 1.3947x over previous
//
#include <hip/hip_runtime.h>
#include <hip/hip_bf16.h>

#define D_MODEL 512
#define D_STATE 32
#define BATCH 8
#define SEQ 4096
#define MROWS (BATCH * SEQ)
#define NBLK 1024

typedef __bf16 bf16;
typedef __bf16 bf16x4 __attribute__((ext_vector_type(4)));
typedef __bf16 bf16x8 __attribute__((ext_vector_type(8)));
typedef float f32x4 __attribute__((ext_vector_type(4)));

#define CHUNK 16
#define BURN 80
#define NCHUNK (SEQ / CHUNK)   // 256 chunks per batch, 2048 chains

// ================= k_A: fully block-local (NO inter-block sync of any kind) =================
// Per block (owns 32 rows): dt-reduce -> convert x->xb(+LDS tile, XOR-swizzled) ->
// X=(I-.5dtA)^-1 fwd-subst (redundant per block, ~2us, parallel across blocks) ->
// s_raw = xb @ B^T via MFMA w/ cooperative per-kt B hi/lo convert -> uB = dt*X@s_raw^T.
// Block 0 also writes A_bar. Blocks 1..64 CW, 65..80 WD.
__global__ __launch_bounds__(256, 4) void k_A(
    const float* __restrict__ x, const float* __restrict__ A, const float* __restrict__ B,
    const float* __restrict__ C, const float* __restrict__ Dv, const float* __restrict__ log_dt,
    const float* __restrict__ W,
    float* __restrict__ A_bar, bf16* __restrict__ CW, bf16* __restrict__ WD,
    float* __restrict__ uB, bf16* __restrict__ xb) {
  __shared__ bf16 xt[32][512];      // 32768 B, XOR granule-swizzled rows
  __shared__ bf16 bfrag[2][1024];   // 4096 B: per-kt B-frags, [0]=hi [1]=lo
  __shared__ float Xs[32][32];      // 4096 B: dt-red scratch -> M -> X (plain [n][kk])
  const int bid = blockIdx.x, t = threadIdx.x;
  const int w = t >> 6, lane = t & 63;
  const int l15 = lane & 15, kg = lane >> 4;
  float* Xf = &Xs[0][0];
  const long rowbase = (long)bid * 32;

  // ---- dt partials (uses Xs as scratch) ----
  {
    float v0 = __expf(log_dt[t]);
    float v1 = __expf(log_dt[t + 256]);
    v0 = fminf(fmaxf(v0, 1e-4f), 1.0f);
    v1 = fminf(fmaxf(v1, 1e-4f), 1.0f);
    Xf[t] = v0 + v1;
  }
  // ---- convert own 32 rows: x -> xb (global) + xt (LDS, swizzled granules) ----
  {
    const int r = t >> 3, c0 = (t & 7) * 4;
    const float* xp = x + (rowbase + r) * D_MODEL + c0;
    bf16* xo = xb + (rowbase + r) * D_MODEL + c0;
    char* xrow = (char*)&xt[r][0];
    const int gb = (t & 7) >> 1;     // granule within kt-group
    const int off8 = (t & 1) * 8;
    const int key = r & 7;
#pragma unroll
    for (int kt = 0; kt < 16; kt++) {
      const f32x4 v = *(const f32x4*)(xp + kt * 32);
      bf16x4 h;
      h[0] = (bf16)v[0]; h[1] = (bf16)v[1]; h[2] = (bf16)v[2]; h[3] = (bf16)v[3];
      *(bf16x4*)(xo + kt * 32) = h;
      *(bf16x4*)(xrow + (((kt * 4 + gb) ^ key) << 4) + off8) = h;
    }
  }
  __syncthreads();
  // ---- dt tree reduce ----
  for (int s2 = 128; s2 > 0; s2 >>= 1) {
    if (t < s2) Xf[t] += Xf[t + s2];
    __syncthreads();
  }
  const float dtv = Xf[0] * (1.0f / 512.0f);
  __syncthreads();
  // ---- stage M = I - 0.5dt*A into Xs ----
  {
    const int i0 = 4 * t;
    const f32x4 av = *(const f32x4*)(A + i0);
    f32x4 mv;
#pragma unroll
    for (int q = 0; q < 4; q++) {
      const int r = (i0 + q) >> 5, c = (i0 + q) & 31;
      mv[q] = (r == c ? 1.0f : 0.0f) - 0.5f * dtv * av[q];
    }
    *(f32x4*)(Xf + i0) = mv;
  }
  __syncthreads();
  // ---- forward substitution: lane j computes column j of X = M^{-1}; in-wave
  //      lockstep guarantees all M reads complete before X overwrites Xs. ----
  if (t < 32) {
    const int j = t;
    float xcol[32];
#pragma unroll
    for (int i = 0; i < 32; i++) {
      float s0 = 0.f, s1 = 0.f, s2 = 0.f, s3 = 0.f;
#pragma unroll
      for (int k = 0; k < 32; k += 4) {
        if (k < i)     s0 -= Xf[i * 32 + k]     * xcol[k];
        if (k + 1 < i) s1 -= Xf[i * 32 + k + 1] * xcol[k + 1];
        if (k + 2 < i) s2 -= Xf[i * 32 + k + 2] * xcol[k + 2];
        if (k + 3 < i) s3 -= Xf[i * 32 + k + 3] * xcol[k + 3];
      }
      const float num = (i == j ? 1.0f : 0.0f) + ((s0 + s1) + (s2 + s3));
      xcol[i] = (i >= j) ? num / Xf[i * 32 + i] : 0.0f;
    }
#pragma unroll
    for (int i = 0; i < 32; i++) Xs[i][j] = xcol[i];   // bank j per lane: conflict-free
  }
  __syncthreads();
  // ---- block 0 only: A_bar = (I + 0.5dt*A) @ X ----
  if (bid == 0) {
    const int i0 = 4 * t;
    const int r = t >> 3;
    f32x4 ov;
#pragma unroll
    for (int q = 0; q < 4; q++) {
      const int c = (i0 + q) & 31;
      float s = 0.f;
#pragma unroll
      for (int k = 0; k < 32; k++) {
        const float p2 = (r == k ? 1.0f : 0.0f) + 0.5f * dtv * A[r * 32 + k];
        s = fmaf(p2, Xf[k * 32 + c], s);
      }
      ov[q] = s;
    }
    *(f32x4*)(A_bar + i0) = ov;
  }
  // ---- s_raw = xb @ B^T: per kt, cooperatively convert B chunk to hi/lo frags, MFMA ----
  const int m = w & 1, nf = w >> 1;
  f32x4 acc = (f32x4)(0.0f);
  {
    const int bn = t >> 3, bc0 = (t & 7) * 4;          // B row, col-offset within chunk
    const int fbase = (((t & 7) >> 1) * 32 + bn) * 8 + (bc0 & 7);
    const int rdoff = (kg * 32 + nf * 16 + l15) * 8;
    const int arow = m * 16 + l15;
    const char* xrow = (const char*)&xt[arow][0];
    const int akey = l15 & 7;                          // arow & 7
#pragma unroll 1
    for (int kt = 0; kt < 16; kt++) {
      const f32x4 bv = *(const f32x4*)(B + bn * D_MODEL + kt * 32 + bc0);
      bf16x4 bh4, bl4;
#pragma unroll
      for (int q = 0; q < 4; q++) {
        const bf16 hi = (bf16)bv[q];
        bh4[q] = hi;
        bl4[q] = (bf16)(bv[q] - (float)hi);
      }
      *(bf16x4*)&bfrag[0][fbase] = bh4;
      *(bf16x4*)&bfrag[1][fbase] = bl4;
      __syncthreads();
      const bf16x8 af = *(const bf16x8*)(xrow + (((kt * 4 + kg) ^ akey) << 4));
      const bf16x8 bh = *(const bf16x8*)&bfrag[0][rdoff];
      const bf16x8 bl = *(const bf16x8*)&bfrag[1][rdoff];
      acc = __builtin_amdgcn_mfma_f32_16x16x32_bf16(af, bh, acc, 0, 0, 0);
      acc = __builtin_amdgcn_mfma_f32_16x16x32_bf16(af, bl, acc, 0, 0, 0);
      __syncthreads();
    }
  }
  // ---- s_raw to LDS (alias xt; xt dead after last MFMA+sync) ----
  float* srw = (float*)&xt[0][0];                      // [32][33] padded
  {
    const int col = nf * 16 + l15;
#pragma unroll
    for (int jj = 0; jj < 4; jj++)
      srw[(m * 16 + kg * 4 + jj) * 33 + col] = acc[jj];
  }
  __syncthreads();
  // ---- uB[row][n] = dt * sum_k X[n][k] * s_raw[row][k]  (rotated k: conflict-free) ----
  {
    const int n = t & 31, r0 = t >> 5;
    float u0 = 0.f, u1 = 0.f, u2 = 0.f, u3 = 0.f;
#pragma unroll
    for (int k2 = 0; k2 < 32; k2++) {
      const int k = (k2 + n) & 31;
      const float xv = Xf[n * 32 + k];
      u0 = fmaf(xv, srw[(r0)      * 33 + k], u0);
      u1 = fmaf(xv, srw[(r0 + 8)  * 33 + k], u1);
      u2 = fmaf(xv, srw[(r0 + 16) * 33 + k], u2);
      u3 = fmaf(xv, srw[(r0 + 24) * 33 + k], u3);
    }
    float* up = uB + (rowbase + r0) * D_STATE + n;
    up[0]                = dtv * u0;
    up[8 * D_STATE]      = dtv * u1;
    up[16 * D_STATE]     = dtv * u2;
    up[24 * D_STATE]     = dtv * u3;
  }
  // ---- side jobs: CW (blocks 1..64), WD (65..80) ----
  if (bid >= 1 && bid <= 64) {
    const int idx = (bid - 1) * 256 + t;
    const int e = idx >> 5, n = idx & 31;
    float s = 0.f;
    for (int d = 0; d < D_MODEL; d += 4) {
      const f32x4 wv = *(const f32x4*)(W + e * D_MODEL + d);
      s = fmaf(wv[0], C[(d + 0) * D_STATE + n], s);
      s = fmaf(wv[1], C[(d + 1) * D_STATE + n], s);
      s = fmaf(wv[2], C[(d + 2) * D_STATE + n], s);
      s = fmaf(wv[3], C[(d + 3) * D_STATE + n], s);
    }
    CW[idx] = (bf16)s;
  } else if (bid >= 65 && bid <= 80) {
#pragma unroll
    for (int jj = 0; jj < 16; jj++) {
      const int i = (bid - 65) * 16384 + jj * 1024 + t * 4;
      const f32x4 wv = *(const f32x4*)(W + i);
      const f32x4 dv = *(const f32x4*)(Dv + (i & 511));
      bf16x4 h;
#pragma unroll
      for (int q = 0; q < 4; q++) h[q] = (bf16)(wv[q] * dv[q]);
      *(bf16x4*)(WD + i) = h;
    }
  }
}

// ---------------- k_scan: standalone; a[] pinned in VGPRs (no remat/reload) ----------------
__global__ void k_scan(const float* __restrict__ uB, const float* __restrict__ A_bar,
                       bf16* __restrict__ Sb, float* __restrict__ fs) {
  __shared__ float sbuf[256];         // 8 groups x 32 state elems
  const int t = threadIdx.x;
  const int g = t >> 5, n = t & 31;
  const int chain = blockIdx.x * 8 + g;
  const int b = chain >> 8;           // 256 chunks per batch
  const int ch = chain & 255;
  const int cs = ch * CHUNK;
  const int t0 = cs - BURN;           // may be negative (u treated as 0 there)
  const int ce = cs + CHUNK;

  float a[32];
#pragma unroll
  for (int k = 0; k < 32; k += 4) {
    const f32x4 v = *(const f32x4*)(A_bar + n * 32 + k);
    a[k] = v[0]; a[k + 1] = v[1]; a[k + 2] = v[2]; a[k + 3] = v[3];
  }
#pragma unroll
  for (int k = 0; k < 32; k++) asm volatile("" : "+v"(a[k]));

  const float* ub = uB + (long)b * SEQ * D_STATE + n;
  bf16* sp = Sb + ((long)b * SEQ + cs) * D_STATE + n;
  float* myslot = &sbuf[g * 32];

  float s = 0.f;
  float ubuf[8], unext[8];
#pragma unroll
  for (int i = 0; i < 8; i++) {
    const int tt = t0 + i;
    ubuf[i] = (tt >= 0) ? ub[(long)tt * D_STATE] : 0.f;
  }
  for (int tg = t0; tg < ce; tg += 8) {
    const int tn = tg + 8;
#pragma unroll
    for (int i = 0; i < 8; i++) {
      const int tt = tn + i;
      unext[i] = (tt >= 0 && tt < ce) ? ub[(long)tt * D_STATE] : 0.f;
    }
#pragma unroll
    for (int i = 0; i < 8; i++) {
      const int tt = tg + i;
      myslot[n] = s;   // ds_write_b32, wave-ordered before the reads below
      const f32x4 s0 = *(const f32x4*)(myslot + 0);
      const f32x4 s1 = *(const f32x4*)(myslot + 4);
      const f32x4 s2 = *(const f32x4*)(myslot + 8);
      const f32x4 s3 = *(const f32x4*)(myslot + 12);
      const f32x4 s4 = *(const f32x4*)(myslot + 16);
      const f32x4 s5 = *(const f32x4*)(myslot + 20);
      const f32x4 s6 = *(const f32x4*)(myslot + 24);
      const f32x4 s7 = *(const f32x4*)(myslot + 28);
      float acc0 = ubuf[i], acc1 = 0.f, acc2 = 0.f, acc3 = 0.f;
#pragma unroll
      for (int q = 0; q < 4; q++) {
        acc0 = fmaf(a[0 + q],  s0[q], acc0);
        acc1 = fmaf(a[4 + q],  s1[q], acc1);
        acc2 = fmaf(a[8 + q],  s2[q], acc2);
        acc3 = fmaf(a[12 + q], s3[q], acc3);
        acc0 = fmaf(a[16 + q], s4[q], acc0);
        acc1 = fmaf(a[20 + q], s5[q], acc1);
        acc2 = fmaf(a[24 + q], s6[q], acc2);
        acc3 = fmaf(a[28 + q], s7[q], acc3);
      }
      const float z = (acc0 + acc1) + (acc2 + acc3);
      const float e = __expf(2.f * z);
      const float r = __builtin_amdgcn_rcpf(e + 1.f);
      s = fmaf(-2.f, r, 1.f);
      if (tt >= cs) sp[(long)(tt - cs) * D_STATE] = (bf16)s;
    }
#pragma unroll
    for (int i = 0; i < 8; i++) ubuf[i] = unext[i];
  }
  if (ch == NCHUNK - 1) fs[b * D_STATE + n] = s;
}

// ---------------- k_out: out = S@CW^T + xb@WD^T + b (bf16 MFMA, 128x128 tile) ----------------
__device__ __forceinline__ void stage_tile(const void* gbase, long row0, long rowStrideB,
                                           int kByte, void* lds, int w, int lane) {
#pragma unroll
  for (int j = 0; j < 2; j++) {
    const int base_off = (w << 11) + (j << 10);
    const int boff = base_off + (lane << 4);
    const int r = boff >> 6;
    const int s = (boff >> 4) & 3;
    const int cb = ((s ^ (r & 3)) << 4);
    const char* src = (const char*)gbase + (row0 + r) * rowStrideB + kByte + cb;
    __builtin_amdgcn_global_load_lds(
        (const __attribute__((address_space(1))) void*)src,
        (__attribute__((address_space(3))) void*)((char*)lds + base_off), 16, 0, 0);
  }
}

__global__ __launch_bounds__(256) void k_out(const bf16* __restrict__ xb,
                                             const bf16* __restrict__ WD,
                                             const bf16* __restrict__ Sb,
                                             const bf16* __restrict__ CW,
                                             const float* __restrict__ bias,
                                             float* __restrict__ out) {
  __shared__ bf16 As[2][128 * 32];
  __shared__ bf16 Bs[2][128 * 32];
  const int tid = threadIdx.x;
  const int w = tid >> 6, lane = tid & 63;
  const int swz = (blockIdx.x & 7) * 128 + (blockIdx.x >> 3);
  const int bm = swz >> 2, bn = swz & 3;
  const long rowbase = (long)bm * 128;
  const long colbase = (long)bn * 128;
  const int wr = w >> 1, wc = w & 1;
  const int l15 = lane & 15, kg = lane >> 4;
  const int kgs = kg ^ (l15 & 3);

  f32x4 acc[4][4];
#pragma unroll
  for (int m = 0; m < 4; m++)
#pragma unroll
    for (int n = 0; n < 4; n++) acc[m][n] = (f32x4)(0.0f);

  const int aoff = (wr * 64 + l15) * 32 + kgs * 8;
  const int boff = (wc * 64 + l15) * 32 + kgs * 8;

  auto STAGE = [&](int ti, int b) {
    if (ti < 16) {
      stage_tile(xb, rowbase, 1024, ti * 64, &As[b][0], w, lane);
      stage_tile(WD, colbase, 1024, ti * 64, &Bs[b][0], w, lane);
    } else {
      stage_tile(Sb, rowbase, 64, 0, &As[b][0], w, lane);
      stage_tile(CW, colbase, 64, 0, &Bs[b][0], w, lane);
    }
  };

  STAGE(0, 0);
  __syncthreads();
#pragma unroll 1
  for (int kt = 0; kt < 17; kt++) {
    const int cur = kt & 1;
    if (kt < 16) STAGE(kt + 1, cur ^ 1);
    bf16x8 af[4], bfr[4];
#pragma unroll
    for (int m = 0; m < 4; m++) af[m] = *(const bf16x8*)&As[cur][aoff + m * 16 * 32];
#pragma unroll
    for (int n = 0; n < 4; n++) bfr[n] = *(const bf16x8*)&Bs[cur][boff + n * 16 * 32];
#pragma unroll
    for (int m = 0; m < 4; m++)
#pragma unroll
      for (int n = 0; n < 4; n++)
        acc[m][n] = __builtin_amdgcn_mfma_f32_16x16x32_bf16(af[m], bfr[n], acc[m][n], 0, 0, 0);
    __syncthreads();
  }
#pragma unroll
  for (int n = 0; n < 4; n++) {
    const int e = (int)colbase + wc * 64 + n * 16 + l15;
    const float bv = bias[e];
#pragma unroll
    for (int m = 0; m < 4; m++) {
      const long r0 = rowbase + wr * 64 + m * 16 + kg * 4;
      const f32x4 v = acc[m][n];
#pragma unroll
      for (int jj = 0; jj < 4; jj++) out[(r0 + jj) * (long)D_MODEL + e] = v[jj] + bv;
    }
  }
}

extern "C" void kernel_launch(void* const* d_in, const int* in_sizes, int n_in,
                              void* d_out, int out_size, void* d_ws, size_t ws_size,
                              hipStream_t stream) {
  const float* x      = (const float*)d_in[0];
  const float* A      = (const float*)d_in[1];
  const float* B      = (const float*)d_in[2];
  const float* C      = (const float*)d_in[3];
  const float* Dv     = (const float*)d_in[4];
  const float* log_dt = (const float*)d_in[5];
  const float* W      = (const float*)d_in[6];
  const float* b_out  = (const float*)d_in[7];
  float* out = (float*)d_out;
  float* fs  = out + (long)MROWS * D_MODEL;  // final_state (8x32) after y

  char* ws = (char*)d_ws;
  float* A_bar = (float*)(ws + 0);                    // 4 KB
  bf16*  CW    = (bf16*)(ws + (68L << 10));           // 32 KB
  bf16*  WD    = (bf16*)(ws + (100L << 10));          // 512 KB
  bf16*  Sb    = (bf16*)(ws + (612L << 10));          // 2 MB
  float* uB    = (float*)(ws + (2660L << 10));        // 4 MB
  bf16*  xb    = (bf16*)(ws + (6756L << 10));         // 32 MB

  k_A<<<dim3(NBLK), dim3(256), 0, stream>>>(x, A, B, C, Dv, log_dt, W,
                                            A_bar, CW, WD, uB, xb);
  k_scan<<<dim3(256), dim3(256), 0, stream>>>(uB, A_bar, Sb, fs);
  k_out<<<dim3((MROWS / 128) * (D_MODEL / 128)), dim3(256), 0, stream>>>(xb, WD, Sb, CW, b_out, out);
}